// Round 13
// baseline (162.218 us; speedup 1.0000x reference)
//
#include <hip/hip_runtime.h>

typedef __attribute__((ext_vector_type(8))) _Float16 half8;
typedef __attribute__((ext_vector_type(4))) _Float16 half4;
typedef __attribute__((ext_vector_type(4))) float f32x4;

#define NB 2
#define CIN 64
#define ICH 32
#define HH 80
#define WW 80
#define NSP 6400
#define KSPLIT 5
#define KRANGE 1280
#define KBLK 128
#define NITER 10
#define QBLK 32
#define QGROUPS 50   /* 128 q-rows per block */

// ---------------------------------------------------------------------------
// Kernel 0: input transpose + weight prep (round-12, body looped `reps` times
// for timing attribution; output byte-identical each rep).
// ---------------------------------------------------------------------------
__global__ __launch_bounds__(256) void nlb_trans_kernel(
    const float* __restrict__ x, const float* __restrict__ x_t,
    const float* __restrict__ shared_w, const float* __restrict__ g_w,
    _Float16* __restrict__ Xf16, _Float16* __restrict__ W9f,
    _Float16* __restrict__ GWf, int reps)
{
    const int bid = blockIdx.x;
    const int tid = threadIdx.x;

    for (int rep = 0; rep < reps; ++rep) {
        if (bid >= 320) {
            int e = (bid - 320) * 256 + tid;
            if (e < 9 * 32 * 64) {
                int c = e & 63, o = (e >> 6) & 31, tap = e >> 11;
                W9f[e] = (_Float16)shared_w[(o * 64 + c) * 9 + tap];
            } else {
                int e2 = e - 9 * 32 * 64;
                GWf[e2] = (_Float16)g_w[e2];
            }
            continue;
        }

        const int src = bid & 1;
        const int b   = (bid >> 1) & 1;
        const int h   = bid >> 2;
        const float* __restrict__ in = src ? x_t : x;

        __shared__ float ts[CIN][WW + 1];

        #pragma unroll
        for (int i = 0; i < 5; ++i) {
            int idx = tid + i * 256;
            int c = idx / 20, w4 = idx % 20;
            float4 v = *(const float4*)(in + ((size_t)(b * CIN + c) * HH + h) * WW + w4 * 4);
            ts[c][w4 * 4 + 0] = v.x;
            ts[c][w4 * 4 + 1] = v.y;
            ts[c][w4 * 4 + 2] = v.z;
            ts[c][w4 * 4 + 3] = v.w;
        }
        __syncthreads();

        _Float16* __restrict__ dst = Xf16 + ((size_t)(src * NB + b) * NSP + h * WW) * CIN;
        #pragma unroll
        for (int i = 0; i < 3; ++i) {
            int idx = tid + i * 256;
            if (idx < 640) {
                int w = idx >> 3, cb = idx & 7;
                half8 o;
                #pragma unroll
                for (int k = 0; k < 8; ++k) o[k] = (_Float16)ts[cb * 8 + k][w];
                *(half8*)(dst + (size_t)w * CIN + cb * 8) = o;
            }
        }
        __syncthreads();   // WAR guard on ts across reps
    }
}

// ---------------------------------------------------------------------------
// Kernel 1: implicit-GEMM conv (round-12, body looped `reps` times).
// ---------------------------------------------------------------------------
__global__ __launch_bounds__(256) void nlb_conv_mfma_kernel(
    const _Float16* __restrict__ Xf16,
    const _Float16* __restrict__ W9f, const _Float16* __restrict__ GWf,
    const float* __restrict__ shared_b, const float* __restrict__ g_b,
    _Float16* __restrict__ Q, _Float16* __restrict__ K, _Float16* __restrict__ Vt,
    int reps)
{
    const int bid = blockIdx.x;
    const int src = bid & 1;
    const int b   = (bid >> 1) & 1;
    const int h   = bid >> 2;

    __shared__ _Float16 xs[3 * 82 * 64];

    const int tid = threadIdx.x;
    const _Float16* __restrict__ Xb = Xf16 + (size_t)(src * NB + b) * NSP * CIN;

    for (int rep = 0; rep < reps; ++rep) {
        #pragma unroll
        for (int i = 0; i < 8; ++i) {
            int idx = tid + i * 256;
            if (idx < 1920) {
                int rr = idx / 640;
                int rem = idx % 640;
                int w  = rem >> 3, cb = rem & 7;
                int wi = w + 1;
                int hr = h + rr - 1;
                half8 v = {};
                if (hr >= 0 && hr < HH)
                    v = *(const half8*)(Xb + ((size_t)(hr * WW + w)) * CIN + cb * 8);
                int slot = cb ^ ((wi + (wi >> 3)) & 7);
                *(half8*)(&xs[(rr * 82 + wi) * 64 + slot * 8]) = v;
            }
        }
        if (tid < 48) {
            int cb = tid & 7;
            int wi = ((tid >> 3) & 1) ? 81 : 0;
            int rr = tid >> 4;
            int slot = cb ^ ((wi + (wi >> 3)) & 7);
            half8 z = {};
            *(half8*)(&xs[(rr * 82 + wi) * 64 + slot * 8]) = z;
        }
        __syncthreads();

        const int wid  = tid >> 6;
        const int lane = tid & 63;
        const int g = lane >> 4, r = lane & 15;
        const int o0 = (wid & 1) * 16;
        const int ti_lo = (wid >> 1) ? 3 : 0;
        const int ti_hi = (wid >> 1) ? 5 : 3;

        half8 aw[9][2];
        #pragma unroll
        for (int tap = 0; tap < 9; ++tap)
            #pragma unroll
            for (int ch = 0; ch < 2; ++ch)
                aw[tap][ch] = *(const half8*)(W9f + ((tap * 32 + o0 + r) * 64 + ch * 32 + g * 8));
        half8 gaf[2];
        if (src) {
            #pragma unroll
            for (int ch = 0; ch < 2; ++ch)
                gaf[ch] = *(const half8*)(GWf + ((o0 + r) * 64 + ch * 32 + g * 8));
        }

        f32x4 biasv, gbv = {0.f, 0.f, 0.f, 0.f};
        #pragma unroll
        for (int j = 0; j < 4; ++j) biasv[j] = shared_b[o0 + g * 4 + j];
        if (src) {
            #pragma unroll
            for (int j = 0; j < 4; ++j) gbv[j] = g_b[o0 + g * 4 + j];
        }

        for (int ti = ti_lo; ti < ti_hi; ++ti) {
            const int n0 = ti * 16;
            const int wi0 = n0 + r;
            f32x4 accE = biasv;
            f32x4 accO = {0.f, 0.f, 0.f, 0.f};
            f32x4 vacc = gbv;
            #pragma unroll
            for (int tap = 0; tap < 9; ++tap) {
                const int kh = tap / 3, kw = tap % 3;
                const int wi = wi0 + kw;
                const int swz = (wi + (wi >> 3)) & 7;
                #pragma unroll
                for (int ch = 0; ch < 2; ++ch) {
                    half8 bf = *(const half8*)(&xs[(kh * 82 + wi) * 64 + (((ch * 4 + g) ^ swz) * 8)]);
                    if (tap & 1) accO = __builtin_amdgcn_mfma_f32_16x16x32_f16(aw[tap][ch], bf, accO, 0, 0, 0);
                    else         accE = __builtin_amdgcn_mfma_f32_16x16x32_f16(aw[tap][ch], bf, accE, 0, 0, 0);
                    if (src && tap == 4)
                        vacc = __builtin_amdgcn_mfma_f32_16x16x32_f16(gaf[ch], bf, vacc, 0, 0, 0);
                }
            }
            const int n = h * WW + n0 + r;
            f32x4 acc;
            #pragma unroll
            for (int j = 0; j < 4; ++j) acc[j] = accE[j] + accO[j];
            half4 pk;
            #pragma unroll
            for (int j = 0; j < 4; ++j) pk[j] = (_Float16)acc[j];
            if (!src) {
                *(half4*)(Q + (size_t)(b * NSP + n) * ICH + o0 + g * 4) = pk;
            } else {
                *(half4*)(K + (size_t)(b * NSP + n) * ICH + o0 + g * 4) = pk;
                #pragma unroll
                for (int j = 0; j < 4; ++j)
                    Vt[(size_t)(b * ICH + o0 + g * 4 + j) * NSP + n] = (_Float16)vacc[j];
            }
        }
        __syncthreads();   // WAR guard on xs across reps
    }
}

// ---------------------------------------------------------------------------
// Kernel 2: flash attention (round-10, byte-identical, single launch).
// ---------------------------------------------------------------------------
#define KPAD 40    /* K LDS row: 80 B  */
#define VPAD 136   /* V LDS row: 272 B */

__global__ __launch_bounds__(256) void nlb_attn_kernel(
    const _Float16* __restrict__ Q, const _Float16* __restrict__ Km,
    const _Float16* __restrict__ Vt,
    float* __restrict__ YU, float* __restrict__ ML)
{
    const int bid = blockIdx.x;
    const int tg  = bid % QGROUPS;
    const int rem = bid / QGROUPS;
    const int b = rem & 1;
    const int s = rem >> 1;

    const int tid  = threadIdx.x;
    const int wid  = tid >> 6;
    const int lane = tid & 63;
    const int g = lane >> 4, r = lane & 15;

    __shared__ __align__(16) _Float16 Kls[2][KBLK][KPAD];
    __shared__ __align__(16) _Float16 Vls[2][ICH][VPAD];

    const _Float16* __restrict__ Qb = Q  + (size_t)b * NSP * ICH;
    const _Float16* __restrict__ Kb = Km + (size_t)b * NSP * ICH + (size_t)s * KRANGE * ICH;
    const _Float16* __restrict__ Vb = Vt + (size_t)b * ICH * NSP + s * KRANGE;

    const f32x4 zero4 = {0.f, 0.f, 0.f, 0.f};

    const int q0 = tg * 128 + wid * QBLK;
    half8 qa[2];
    #pragma unroll
    for (int qf = 0; qf < 2; ++qf)
        qa[qf] = *(const half8*)(Qb + (size_t)(q0 + qf * 16 + r) * ICH + g * 8);

    f32x4 yacc[2][2];
    float m2[2], lp[2];
    #pragma unroll
    for (int qf = 0; qf < 2; ++qf) {
        yacc[qf][0] = zero4; yacc[qf][1] = zero4;
        m2[qf] = -1e30f; lp[qf] = 0.f;
    }

    const int ka_r = tid >> 2,          ka_c = tid & 3;
    const int kb_r = (tid + 256) >> 2,  kb_c = (tid + 256) & 3;
    const int va_r = tid >> 4,          va_c = tid & 15;
    const int vb_r = (tid + 256) >> 4,  vb_c = (tid + 256) & 15;

    {
        *(half8*)(&Kls[0][ka_r][ka_c * 8]) = *(const half8*)(Kb + (size_t)ka_r * ICH + ka_c * 8);
        *(half8*)(&Kls[0][kb_r][kb_c * 8]) = *(const half8*)(Kb + (size_t)kb_r * ICH + kb_c * 8);
        *(half8*)(&Vls[0][va_r][va_c * 8]) = *(const half8*)(Vb + (size_t)va_r * NSP + va_c * 8);
        *(half8*)(&Vls[0][vb_r][vb_c * 8]) = *(const half8*)(Vb + (size_t)vb_r * NSP + vb_c * 8);
    }
    __syncthreads();

    int cur = 0;
    for (int it = 0; it < NITER; ++it) {
        const bool more = (it + 1 < NITER);
        half8 kst0, kst1, vst0, vst1;
        if (more) {
            const _Float16* Kn = Kb + (size_t)(it + 1) * KBLK * ICH;
            const _Float16* Vn = Vb + (size_t)(it + 1) * KBLK;
            kst0 = *(const half8*)(Kn + (size_t)ka_r * ICH + ka_c * 8);
            kst1 = *(const half8*)(Kn + (size_t)kb_r * ICH + kb_c * 8);
            vst0 = *(const half8*)(Vn + (size_t)va_r * NSP + va_c * 8);
            vst1 = *(const half8*)(Vn + (size_t)vb_r * NSP + vb_c * 8);
        }

        half8 kf[8];
        #pragma unroll
        for (int kh = 0; kh < 8; ++kh)
            kf[kh] = *(const half8*)(&Kls[cur][kh * 16 + r][g * 8]);

        #pragma unroll
        for (int qf = 0; qf < 2; ++qf) {
            f32x4 sa[8];
            __builtin_amdgcn_s_setprio(1);
            #pragma unroll
            for (int kh = 0; kh < 8; ++kh)
                sa[kh] = __builtin_amdgcn_mfma_f32_16x16x32_f16(kf[kh], qa[qf], zero4, 0, 0, 0);
            __builtin_amdgcn_s_setprio(0);

            float vmax = -1e30f;
            #pragma unroll
            for (int kh = 0; kh < 8; ++kh)
                vmax = fmaxf(vmax, fmaxf(fmaxf(sa[kh][0], sa[kh][1]),
                                         fmaxf(sa[kh][2], sa[kh][3])));
            if (__any(vmax - m2[qf] > 8.f)) {
                float tm = vmax;
                tm = fmaxf(tm, __shfl_xor(tm, 16));
                tm = fmaxf(tm, __shfl_xor(tm, 32));
                float mn = fmaxf(m2[qf], tm);
                float sc = __expf(m2[qf] - mn);
                m2[qf] = mn; lp[qf] *= sc;
                #pragma unroll
                for (int j = 0; j < 4; ++j) { yacc[qf][0][j] *= sc; yacc[qf][1][j] *= sc; }
            }

            #pragma unroll
            for (int kh = 0; kh < 8; ++kh) {
                half4 pk; float ls = 0.f;
                #pragma unroll
                for (int j = 0; j < 4; ++j) {
                    float p = __expf(sa[kh][j] - m2[qf]);
                    ls += p; pk[j] = (_Float16)p;
                }
                lp[qf] += ls;
                half4 vfa = *(const half4*)(&Vls[cur][r][kh * 16 + g * 4]);
                half4 vfb = *(const half4*)(&Vls[cur][16 + r][kh * 16 + g * 4]);
                yacc[qf][0] = __builtin_amdgcn_mfma_f32_16x16x16f16(vfa, pk, yacc[qf][0], 0, 0, 0);
                yacc[qf][1] = __builtin_amdgcn_mfma_f32_16x16x16f16(vfb, pk, yacc[qf][1], 0, 0, 0);
            }
        }

        if (more) {
            *(half8*)(&Kls[cur ^ 1][ka_r][ka_c * 8]) = kst0;
            *(half8*)(&Kls[cur ^ 1][kb_r][kb_c * 8]) = kst1;
            *(half8*)(&Vls[cur ^ 1][va_r][va_c * 8]) = vst0;
            *(half8*)(&Vls[cur ^ 1][vb_r][vb_c * 8]) = vst1;
        }
        __syncthreads();
        cur ^= 1;
    }

    #pragma unroll
    for (int qf = 0; qf < 2; ++qf) {
        float lv = lp[qf];
        lv += __shfl_xor(lv, 16);
        lv += __shfl_xor(lv, 32);
        if (g == 0) {
            size_t base = ((size_t)(s * NB + b) * NSP + q0 + qf * 16 + r) * 2;
            ML[base + 0] = m2[qf];
            ML[base + 1] = lv;
        }
        #pragma unroll
        for (int ch = 0; ch < 2; ++ch)
            *(f32x4*)(YU + ((size_t)(s * NB + b) * NSP + q0 + qf * 16 + r) * ICH
                      + ch * 16 + g * 4) = yacc[qf][ch];
    }
}

// ---------------------------------------------------------------------------
// Kernel 3: combine (round-12, body looped `reps` times).
// ---------------------------------------------------------------------------
__global__ __launch_bounds__(256) void nlb_combine_kernel(
    const float* __restrict__ YU, const float* __restrict__ ML,
    const float* __restrict__ W_w, const float* __restrict__ W_b,
    const float* __restrict__ x, float* __restrict__ out, int reps)
{
    const int bid = blockIdx.x;
    const int b = bid / 200;
    const int rowbase = (bid % 200) * 32;

    __shared__ float ylds[32][33];
    __shared__ float wwl[CIN * ICH];

    const int tid = threadIdx.x;

    for (int rep = 0; rep < reps; ++rep) {
        for (int e = tid; e < CIN * ICH; e += 256) wwl[e] = W_w[e];

        #pragma unroll
        for (int i = 0; i < 4; ++i) {
            int idx = tid + i * 256;
            int row = idx >> 5, c = idx & 31;
            int grow = rowbase + row;
            float m[KSPLIT], lv[KSPLIT], M = -1e30f;
            #pragma unroll
            for (int s2 = 0; s2 < KSPLIT; ++s2) {
                size_t base = ((size_t)(s2 * NB + b) * NSP + grow) * 2;
                m[s2]  = ML[base + 0];
                lv[s2] = ML[base + 1];
                M = fmaxf(M, m[s2]);
            }
            float denom = 0.f, acc = 0.f;
            #pragma unroll
            for (int s2 = 0; s2 < KSPLIT; ++s2) {
                float e2 = __expf(m[s2] - M);
                denom += lv[s2] * e2;
                acc += YU[((size_t)(s2 * NB + b) * NSP + grow) * ICH + c] * e2;
            }
            ylds[row][c] = acc / denom;
        }
        __syncthreads();

        const int row = tid & 31;
        const int o0  = tid >> 5;
        #pragma unroll
        for (int k = 0; k < 8; ++k) {
            int o = o0 * 8 + k;
            size_t gi = (size_t)(b * CIN + o) * NSP + rowbase + row;
            float accv = W_b[o] + x[gi];
            #pragma unroll
            for (int c = 0; c < ICH; ++c) accv += wwl[o * ICH + c] * ylds[row][c];
            out[gi] = accv;
        }
        __syncthreads();   // WAR guard on ylds/wwl across reps
    }
}

// ---------------------------------------------------------------------------
extern "C" void kernel_launch(void* const* d_in, const int* in_sizes, int n_in,
                              void* d_out, int out_size, void* d_ws, size_t ws_size,
                              hipStream_t stream) {
    const float* x        = (const float*)d_in[0];
    const float* x_t      = (const float*)d_in[1];
    const float* g_w      = (const float*)d_in[2];
    const float* g_b      = (const float*)d_in[3];
    const float* W_w      = (const float*)d_in[4];
    const float* W_b      = (const float*)d_in[5];
    const float* shared_w = (const float*)d_in[6];
    const float* shared_b = (const float*)d_in[7];
    float* out = (float*)d_out;

    char* ws = (char*)d_ws;
    _Float16* Q    = (_Float16*)(ws);                  //   819,200 B
    _Float16* K    = (_Float16*)(ws + 819200);         //   819,200 B
    _Float16* Vt   = (_Float16*)(ws + 1638400);        //   819,200 B
    float*    YU   = (float*)(ws + 2457600);           // 8,192,000 B
    float*    ML   = (float*)(ws + 10649600);          //   512,000 B
    _Float16* W9f  = (_Float16*)(ws + 11161600);       //    36,864 B
    _Float16* GWf  = (_Float16*)(ws + 11198464);       //     4,096 B
    _Float16* Xf16 = (_Float16*)(ws + 11202560);       // 3,276,800 B (total ~14.5 MB)

    // MEASUREMENT ROUND: trans x32, conv x12, combine x12 (inner-repeat) so each
    // dispatch exceeds the ~40us harness fills and appears in rocprof top-5 with
    // its own counters. per-kernel dur = dispatch_dur / reps. attn single (known 29us).
    hipLaunchKernelGGL(nlb_trans_kernel, dim3(400), dim3(256), 0, stream,
                       x, x_t, shared_w, g_w, Xf16, W9f, GWf, 32);
    hipLaunchKernelGGL(nlb_conv_mfma_kernel, dim3(320), dim3(256), 0, stream,
                       Xf16, W9f, GWf, shared_b, g_b, Q, K, Vt, 12);
    hipLaunchKernelGGL(nlb_attn_kernel, dim3(NB * QGROUPS * KSPLIT), dim3(256), 0, stream,
                       Q, K, Vt, YU, ML);
    hipLaunchKernelGGL(nlb_combine_kernel, dim3(400), dim3(256), 0, stream,
                       YU, ML, W_w, W_b, x, out, 12);
}

// Round 14
// 91.398 us; speedup vs baseline: 1.7749x; 1.7749x over previous
//
#include <hip/hip_runtime.h>

typedef __attribute__((ext_vector_type(8))) _Float16 half8;
typedef __attribute__((ext_vector_type(4))) _Float16 half4;
typedef __attribute__((ext_vector_type(4))) float f32x4;

#define NB 2
#define CIN 64
#define ICH 32
#define HH 80
#define WW 80
#define NSP 6400
#define KSPLIT 5
#define KRANGE 1280
#define KBLK 128
#define NITER 10
#define QBLK 32
#define QGROUPS 50   /* 128 q-rows per block */

// ---------------------------------------------------------------------------
// Kernel 0: input transpose (f32 NCHW -> f16 [src][b][n][c]) + weight prep.
// ---------------------------------------------------------------------------
__global__ __launch_bounds__(256) void nlb_trans_kernel(
    const float* __restrict__ x, const float* __restrict__ x_t,
    const float* __restrict__ shared_w, const float* __restrict__ g_w,
    _Float16* __restrict__ Xf16, _Float16* __restrict__ W9f,
    _Float16* __restrict__ GWf)
{
    const int bid = blockIdx.x;
    const int tid = threadIdx.x;

    if (bid >= 320) {
        int e = (bid - 320) * 256 + tid;
        if (e < 9 * 32 * 64) {
            int c = e & 63, o = (e >> 6) & 31, tap = e >> 11;
            W9f[e] = (_Float16)shared_w[(o * 64 + c) * 9 + tap];
        } else {
            int e2 = e - 9 * 32 * 64;
            GWf[e2] = (_Float16)g_w[e2];
        }
        return;
    }

    const int src = bid & 1;
    const int b   = (bid >> 1) & 1;
    const int h   = bid >> 2;
    const float* __restrict__ in = src ? x_t : x;

    __shared__ float ts[CIN][WW + 1];

    #pragma unroll
    for (int i = 0; i < 5; ++i) {
        int idx = tid + i * 256;
        int c = idx / 20, w4 = idx % 20;
        float4 v = *(const float4*)(in + ((size_t)(b * CIN + c) * HH + h) * WW + w4 * 4);
        ts[c][w4 * 4 + 0] = v.x;
        ts[c][w4 * 4 + 1] = v.y;
        ts[c][w4 * 4 + 2] = v.z;
        ts[c][w4 * 4 + 3] = v.w;
    }
    __syncthreads();

    _Float16* __restrict__ dst = Xf16 + ((size_t)(src * NB + b) * NSP + h * WW) * CIN;
    #pragma unroll
    for (int i = 0; i < 3; ++i) {
        int idx = tid + i * 256;
        if (idx < 640) {
            int w = idx >> 3, cb = idx & 7;
            half8 o;
            #pragma unroll
            for (int k = 0; k < 8; ++k) o[k] = (_Float16)ts[cb * 8 + k][w];
            *(half8*)(dst + (size_t)w * CIN + cb * 8) = o;
        }
    }
}

// ---------------------------------------------------------------------------
// Kernel 1: implicit-GEMM 3x3 conv via MFMA + fused 1x1 g-conv (round-12).
// ---------------------------------------------------------------------------
__global__ __launch_bounds__(256) void nlb_conv_mfma_kernel(
    const _Float16* __restrict__ Xf16,
    const _Float16* __restrict__ W9f, const _Float16* __restrict__ GWf,
    const float* __restrict__ shared_b, const float* __restrict__ g_b,
    _Float16* __restrict__ Q, _Float16* __restrict__ K, _Float16* __restrict__ Vt)
{
    const int bid = blockIdx.x;
    const int src = bid & 1;
    const int b   = (bid >> 1) & 1;
    const int h   = bid >> 2;

    __shared__ _Float16 xs[3 * 82 * 64];

    const int tid = threadIdx.x;
    const _Float16* __restrict__ Xb = Xf16 + (size_t)(src * NB + b) * NSP * CIN;

    #pragma unroll
    for (int i = 0; i < 8; ++i) {
        int idx = tid + i * 256;
        if (idx < 1920) {
            int rr = idx / 640;
            int rem = idx % 640;
            int w  = rem >> 3, cb = rem & 7;
            int wi = w + 1;
            int hr = h + rr - 1;
            half8 v = {};
            if (hr >= 0 && hr < HH)
                v = *(const half8*)(Xb + ((size_t)(hr * WW + w)) * CIN + cb * 8);
            int slot = cb ^ ((wi + (wi >> 3)) & 7);
            *(half8*)(&xs[(rr * 82 + wi) * 64 + slot * 8]) = v;
        }
    }
    if (tid < 48) {
        int cb = tid & 7;
        int wi = ((tid >> 3) & 1) ? 81 : 0;
        int rr = tid >> 4;
        int slot = cb ^ ((wi + (wi >> 3)) & 7);
        half8 z = {};
        *(half8*)(&xs[(rr * 82 + wi) * 64 + slot * 8]) = z;
    }
    __syncthreads();

    const int wid  = tid >> 6;
    const int lane = tid & 63;
    const int g = lane >> 4, r = lane & 15;
    const int o0 = (wid & 1) * 16;
    const int ti_lo = (wid >> 1) ? 3 : 0;
    const int ti_hi = (wid >> 1) ? 5 : 3;

    half8 aw[9][2];
    #pragma unroll
    for (int tap = 0; tap < 9; ++tap)
        #pragma unroll
        for (int ch = 0; ch < 2; ++ch)
            aw[tap][ch] = *(const half8*)(W9f + ((tap * 32 + o0 + r) * 64 + ch * 32 + g * 8));
    half8 gaf[2];
    if (src) {
        #pragma unroll
        for (int ch = 0; ch < 2; ++ch)
            gaf[ch] = *(const half8*)(GWf + ((o0 + r) * 64 + ch * 32 + g * 8));
    }

    f32x4 biasv, gbv = {0.f, 0.f, 0.f, 0.f};
    #pragma unroll
    for (int j = 0; j < 4; ++j) biasv[j] = shared_b[o0 + g * 4 + j];
    if (src) {
        #pragma unroll
        for (int j = 0; j < 4; ++j) gbv[j] = g_b[o0 + g * 4 + j];
    }

    for (int ti = ti_lo; ti < ti_hi; ++ti) {
        const int n0 = ti * 16;
        const int wi0 = n0 + r;
        f32x4 accE = biasv;
        f32x4 accO = {0.f, 0.f, 0.f, 0.f};
        f32x4 vacc = gbv;
        #pragma unroll
        for (int tap = 0; tap < 9; ++tap) {
            const int kh = tap / 3, kw = tap % 3;
            const int wi = wi0 + kw;
            const int swz = (wi + (wi >> 3)) & 7;
            #pragma unroll
            for (int ch = 0; ch < 2; ++ch) {
                half8 bf = *(const half8*)(&xs[(kh * 82 + wi) * 64 + (((ch * 4 + g) ^ swz) * 8)]);
                if (tap & 1) accO = __builtin_amdgcn_mfma_f32_16x16x32_f16(aw[tap][ch], bf, accO, 0, 0, 0);
                else         accE = __builtin_amdgcn_mfma_f32_16x16x32_f16(aw[tap][ch], bf, accE, 0, 0, 0);
                if (src && tap == 4)
                    vacc = __builtin_amdgcn_mfma_f32_16x16x32_f16(gaf[ch], bf, vacc, 0, 0, 0);
            }
        }
        const int n = h * WW + n0 + r;
        f32x4 acc;
        #pragma unroll
        for (int j = 0; j < 4; ++j) acc[j] = accE[j] + accO[j];
        half4 pk;
        #pragma unroll
        for (int j = 0; j < 4; ++j) pk[j] = (_Float16)acc[j];
        if (!src) {
            *(half4*)(Q + (size_t)(b * NSP + n) * ICH + o0 + g * 4) = pk;
        } else {
            *(half4*)(K + (size_t)(b * NSP + n) * ICH + o0 + g * 4) = pk;
            #pragma unroll
            for (int j = 0; j < 4; ++j)
                Vt[(size_t)(b * ICH + o0 + g * 4 + j) * NSP + n] = (_Float16)vacc[j];
        }
    }
}

// ---------------------------------------------------------------------------
// Kernel 2: flash attention (round-10 math, byte-identical) + FUSED split-k
// combine: after writing YU/ML, each block increments a per-(b,tg) counter;
// the last-arriving of the 5 splits normalizes + applies W 1x1 + bias +
// residual for its 128 rows (reusing the attn LDS). Output is identical
// regardless of arrival order (fixed-order reduction over splits).
// ---------------------------------------------------------------------------
#define KPAD 40    /* K LDS row: 80 B  */
#define VPAD 136   /* V LDS row: 272 B */

__global__ __launch_bounds__(256) void nlb_attn_fused_kernel(
    const _Float16* __restrict__ Q, const _Float16* __restrict__ Km,
    const _Float16* __restrict__ Vt,
    float* __restrict__ YU, float* __restrict__ ML,
    unsigned* __restrict__ cnt,
    const float* __restrict__ W_w, const float* __restrict__ W_b,
    const float* __restrict__ x, float* __restrict__ out)
{
    const int bid = blockIdx.x;
    const int tg  = bid % QGROUPS;
    const int rem = bid / QGROUPS;
    const int b = rem & 1;
    const int s = rem >> 1;

    const int tid  = threadIdx.x;
    const int wid  = tid >> 6;
    const int lane = tid & 63;
    const int g = lane >> 4, r = lane & 15;

    __shared__ __align__(16) char smem[2 * KBLK * KPAD * 2 + 2 * ICH * VPAD * 2];
    _Float16 (*Kls)[KBLK][KPAD] = (_Float16 (*)[KBLK][KPAD])smem;
    _Float16 (*Vls)[ICH][VPAD]  = (_Float16 (*)[ICH][VPAD])(smem + 2 * KBLK * KPAD * 2);

    const _Float16* __restrict__ Qb = Q  + (size_t)b * NSP * ICH;
    const _Float16* __restrict__ Kb = Km + (size_t)b * NSP * ICH + (size_t)s * KRANGE * ICH;
    const _Float16* __restrict__ Vb = Vt + (size_t)b * ICH * NSP + s * KRANGE;

    const f32x4 zero4 = {0.f, 0.f, 0.f, 0.f};

    const int q0 = tg * 128 + wid * QBLK;
    half8 qa[2];
    #pragma unroll
    for (int qf = 0; qf < 2; ++qf)
        qa[qf] = *(const half8*)(Qb + (size_t)(q0 + qf * 16 + r) * ICH + g * 8);

    f32x4 yacc[2][2];
    float m2[2], lp[2];
    #pragma unroll
    for (int qf = 0; qf < 2; ++qf) {
        yacc[qf][0] = zero4; yacc[qf][1] = zero4;
        m2[qf] = -1e30f; lp[qf] = 0.f;
    }

    const int ka_r = tid >> 2,          ka_c = tid & 3;
    const int kb_r = (tid + 256) >> 2,  kb_c = (tid + 256) & 3;
    const int va_r = tid >> 4,          va_c = tid & 15;
    const int vb_r = (tid + 256) >> 4,  vb_c = (tid + 256) & 15;

    {
        *(half8*)(&Kls[0][ka_r][ka_c * 8]) = *(const half8*)(Kb + (size_t)ka_r * ICH + ka_c * 8);
        *(half8*)(&Kls[0][kb_r][kb_c * 8]) = *(const half8*)(Kb + (size_t)kb_r * ICH + kb_c * 8);
        *(half8*)(&Vls[0][va_r][va_c * 8]) = *(const half8*)(Vb + (size_t)va_r * NSP + va_c * 8);
        *(half8*)(&Vls[0][vb_r][vb_c * 8]) = *(const half8*)(Vb + (size_t)vb_r * NSP + vb_c * 8);
    }
    __syncthreads();

    int cur = 0;
    for (int it = 0; it < NITER; ++it) {
        const bool more = (it + 1 < NITER);
        half8 kst0, kst1, vst0, vst1;
        if (more) {
            const _Float16* Kn = Kb + (size_t)(it + 1) * KBLK * ICH;
            const _Float16* Vn = Vb + (size_t)(it + 1) * KBLK;
            kst0 = *(const half8*)(Kn + (size_t)ka_r * ICH + ka_c * 8);
            kst1 = *(const half8*)(Kn + (size_t)kb_r * ICH + kb_c * 8);
            vst0 = *(const half8*)(Vn + (size_t)va_r * NSP + va_c * 8);
            vst1 = *(const half8*)(Vn + (size_t)vb_r * NSP + vb_c * 8);
        }

        half8 kf[8];
        #pragma unroll
        for (int kh = 0; kh < 8; ++kh)
            kf[kh] = *(const half8*)(&Kls[cur][kh * 16 + r][g * 8]);

        #pragma unroll
        for (int qf = 0; qf < 2; ++qf) {
            f32x4 sa[8];
            __builtin_amdgcn_s_setprio(1);
            #pragma unroll
            for (int kh = 0; kh < 8; ++kh)
                sa[kh] = __builtin_amdgcn_mfma_f32_16x16x32_f16(kf[kh], qa[qf], zero4, 0, 0, 0);
            __builtin_amdgcn_s_setprio(0);

            float vmax = -1e30f;
            #pragma unroll
            for (int kh = 0; kh < 8; ++kh)
                vmax = fmaxf(vmax, fmaxf(fmaxf(sa[kh][0], sa[kh][1]),
                                         fmaxf(sa[kh][2], sa[kh][3])));
            if (__any(vmax - m2[qf] > 8.f)) {
                float tm = vmax;
                tm = fmaxf(tm, __shfl_xor(tm, 16));
                tm = fmaxf(tm, __shfl_xor(tm, 32));
                float mn = fmaxf(m2[qf], tm);
                float sc = __expf(m2[qf] - mn);
                m2[qf] = mn; lp[qf] *= sc;
                #pragma unroll
                for (int j = 0; j < 4; ++j) { yacc[qf][0][j] *= sc; yacc[qf][1][j] *= sc; }
            }

            #pragma unroll
            for (int kh = 0; kh < 8; ++kh) {
                half4 pk; float ls = 0.f;
                #pragma unroll
                for (int j = 0; j < 4; ++j) {
                    float p = __expf(sa[kh][j] - m2[qf]);
                    ls += p; pk[j] = (_Float16)p;
                }
                lp[qf] += ls;
                half4 vfa = *(const half4*)(&Vls[cur][r][kh * 16 + g * 4]);
                half4 vfb = *(const half4*)(&Vls[cur][16 + r][kh * 16 + g * 4]);
                yacc[qf][0] = __builtin_amdgcn_mfma_f32_16x16x16f16(vfa, pk, yacc[qf][0], 0, 0, 0);
                yacc[qf][1] = __builtin_amdgcn_mfma_f32_16x16x16f16(vfb, pk, yacc[qf][1], 0, 0, 0);
            }
        }

        if (more) {
            *(half8*)(&Kls[cur ^ 1][ka_r][ka_c * 8]) = kst0;
            *(half8*)(&Kls[cur ^ 1][kb_r][kb_c * 8]) = kst1;
            *(half8*)(&Vls[cur ^ 1][va_r][va_c * 8]) = vst0;
            *(half8*)(&Vls[cur ^ 1][vb_r][vb_c * 8]) = vst1;
        }
        __syncthreads();
        cur ^= 1;
    }

    #pragma unroll
    for (int qf = 0; qf < 2; ++qf) {
        float lv = lp[qf];
        lv += __shfl_xor(lv, 16);
        lv += __shfl_xor(lv, 32);
        if (g == 0) {
            size_t base = ((size_t)(s * NB + b) * NSP + q0 + qf * 16 + r) * 2;
            ML[base + 0] = m2[qf];
            ML[base + 1] = lv;
        }
        #pragma unroll
        for (int ch = 0; ch < 2; ++ch)
            *(f32x4*)(YU + ((size_t)(s * NB + b) * NSP + q0 + qf * 16 + r) * ICH
                      + ch * 16 + g * 4) = yacc[qf][ch];
    }

    // ---- fused split-k combine: last-arriving block does the reduction ----
    __syncthreads();                      // all YU/ML stores issued + vm-drained
    __shared__ int isLast;
    if (tid == 0) {
        __threadfence();                  // release: device-scope visibility
        unsigned old = atomicAdd(&cnt[b * QGROUPS + tg], 1u);
        isLast = (old == KSPLIT - 1);
    }
    __syncthreads();
    if (!isLast) return;
    __threadfence();                      // acquire: invalidate stale cache

    float* wwl        = (float*)smem;                     // 8192 B
    float (*ylds)[33] = (float (*)[33])(smem + 8192);     // 4224 B

    for (int e = tid; e < CIN * ICH; e += 256) wwl[e] = W_w[e];

    const int rowg = tg * 128;
    for (int chunk = 0; chunk < 4; ++chunk) {
        const int rowbase = rowg + chunk * 32;
        __syncthreads();                  // wwl ready / ylds reusable
        #pragma unroll
        for (int i = 0; i < 4; ++i) {
            int idx = tid + i * 256;
            int row = idx >> 5, c = idx & 31;
            int grow = rowbase + row;
            float m[KSPLIT], lv[KSPLIT], M = -1e30f;
            #pragma unroll
            for (int s2 = 0; s2 < KSPLIT; ++s2) {
                size_t base = ((size_t)(s2 * NB + b) * NSP + grow) * 2;
                m[s2]  = ML[base + 0];
                lv[s2] = ML[base + 1];
                M = fmaxf(M, m[s2]);
            }
            float denom = 0.f, acc = 0.f;
            #pragma unroll
            for (int s2 = 0; s2 < KSPLIT; ++s2) {
                float e2 = __expf(m[s2] - M);
                denom += lv[s2] * e2;
                acc += YU[((size_t)(s2 * NB + b) * NSP + grow) * ICH + c] * e2;
            }
            ylds[row][c] = acc / denom;
        }
        __syncthreads();
        const int row = tid & 31;
        const int o0  = tid >> 5;
        #pragma unroll
        for (int k = 0; k < 8; ++k) {
            int o = o0 * 8 + k;
            size_t gi = (size_t)(b * CIN + o) * NSP + rowbase + row;
            float accv = W_b[o] + x[gi];
            #pragma unroll
            for (int c = 0; c < 32; ++c) accv += wwl[o * ICH + c] * ylds[row][c];
            out[gi] = accv;
        }
    }
}

// ---------------------------------------------------------------------------
extern "C" void kernel_launch(void* const* d_in, const int* in_sizes, int n_in,
                              void* d_out, int out_size, void* d_ws, size_t ws_size,
                              hipStream_t stream) {
    const float* x        = (const float*)d_in[0];
    const float* x_t      = (const float*)d_in[1];
    const float* g_w      = (const float*)d_in[2];
    const float* g_b      = (const float*)d_in[3];
    const float* W_w      = (const float*)d_in[4];
    const float* W_b      = (const float*)d_in[5];
    const float* shared_w = (const float*)d_in[6];
    const float* shared_b = (const float*)d_in[7];
    float* out = (float*)d_out;

    char* ws = (char*)d_ws;
    _Float16* Q    = (_Float16*)(ws);                  //   819,200 B
    _Float16* K    = (_Float16*)(ws + 819200);         //   819,200 B
    _Float16* Vt   = (_Float16*)(ws + 1638400);        //   819,200 B
    float*    YU   = (float*)(ws + 2457600);           // 8,192,000 B
    float*    ML   = (float*)(ws + 10649600);          //   512,000 B
    _Float16* W9f  = (_Float16*)(ws + 11161600);       //    36,864 B
    _Float16* GWf  = (_Float16*)(ws + 11198464);       //     4,096 B
    _Float16* Xf16 = (_Float16*)(ws + 11202560);       // 3,276,800 B
    unsigned* cnt  = (unsigned*)(ws + 14479360);       //       400 B (~14.5 MB)

    hipMemsetAsync(cnt, 0, NB * QGROUPS * sizeof(unsigned), stream);
    hipLaunchKernelGGL(nlb_trans_kernel, dim3(400), dim3(256), 0, stream,
                       x, x_t, shared_w, g_w, Xf16, W9f, GWf);
    hipLaunchKernelGGL(nlb_conv_mfma_kernel, dim3(320), dim3(256), 0, stream,
                       Xf16, W9f, GWf, shared_b, g_b, Q, K, Vt);
    hipLaunchKernelGGL(nlb_attn_fused_kernel, dim3(NB * QGROUPS * KSPLIT), dim3(256), 0, stream,
                       Q, K, Vt, YU, ML, cnt, W_w, W_b, x, out);
}

// Round 15
// 60.235 us; speedup vs baseline: 2.6931x; 1.5173x over previous
//
#include <hip/hip_runtime.h>

typedef __attribute__((ext_vector_type(8))) _Float16 half8;
typedef __attribute__((ext_vector_type(4))) _Float16 half4;
typedef __attribute__((ext_vector_type(4))) float f32x4;

#define NB 2
#define CIN 64
#define ICH 32
#define HH 80
#define WW 80
#define NSP 6400
#define KSPLIT 5
#define KRANGE 1280
#define KBLK 128
#define NITER 10
#define QBLK 32
#define QGROUPS 50   /* 128 q-rows per block */

// ---------------------------------------------------------------------------
// Kernel 0: input transpose (f32 NCHW -> f16 [src][b][n][c]) + weight prep.
// ---------------------------------------------------------------------------
__global__ __launch_bounds__(256) void nlb_trans_kernel(
    const float* __restrict__ x, const float* __restrict__ x_t,
    const float* __restrict__ shared_w, const float* __restrict__ g_w,
    _Float16* __restrict__ Xf16, _Float16* __restrict__ W9f,
    _Float16* __restrict__ GWf)
{
    const int bid = blockIdx.x;
    const int tid = threadIdx.x;

    if (bid >= 320) {
        int e = (bid - 320) * 256 + tid;
        if (e < 9 * 32 * 64) {
            int c = e & 63, o = (e >> 6) & 31, tap = e >> 11;
            W9f[e] = (_Float16)shared_w[(o * 64 + c) * 9 + tap];
        } else {
            int e2 = e - 9 * 32 * 64;
            GWf[e2] = (_Float16)g_w[e2];
        }
        return;
    }

    const int src = bid & 1;
    const int b   = (bid >> 1) & 1;
    const int h   = bid >> 2;
    const float* __restrict__ in = src ? x_t : x;

    __shared__ float ts[CIN][WW + 1];

    #pragma unroll
    for (int i = 0; i < 5; ++i) {
        int idx = tid + i * 256;
        int c = idx / 20, w4 = idx % 20;
        float4 v = *(const float4*)(in + ((size_t)(b * CIN + c) * HH + h) * WW + w4 * 4);
        ts[c][w4 * 4 + 0] = v.x;
        ts[c][w4 * 4 + 1] = v.y;
        ts[c][w4 * 4 + 2] = v.z;
        ts[c][w4 * 4 + 3] = v.w;
    }
    __syncthreads();

    _Float16* __restrict__ dst = Xf16 + ((size_t)(src * NB + b) * NSP + h * WW) * CIN;
    #pragma unroll
    for (int i = 0; i < 3; ++i) {
        int idx = tid + i * 256;
        if (idx < 640) {
            int w = idx >> 3, cb = idx & 7;
            half8 o;
            #pragma unroll
            for (int k = 0; k < 8; ++k) o[k] = (_Float16)ts[cb * 8 + k][w];
            *(half8*)(dst + (size_t)w * CIN + cb * 8) = o;
        }
    }
}

// ---------------------------------------------------------------------------
// Kernel 1: implicit-GEMM 3x3 conv via MFMA + fused 1x1 g-conv (round-12).
// ---------------------------------------------------------------------------
__global__ __launch_bounds__(256) void nlb_conv_mfma_kernel(
    const _Float16* __restrict__ Xf16,
    const _Float16* __restrict__ W9f, const _Float16* __restrict__ GWf,
    const float* __restrict__ shared_b, const float* __restrict__ g_b,
    _Float16* __restrict__ Q, _Float16* __restrict__ K, _Float16* __restrict__ Vt)
{
    const int bid = blockIdx.x;
    const int src = bid & 1;
    const int b   = (bid >> 1) & 1;
    const int h   = bid >> 2;

    __shared__ _Float16 xs[3 * 82 * 64];

    const int tid = threadIdx.x;
    const _Float16* __restrict__ Xb = Xf16 + (size_t)(src * NB + b) * NSP * CIN;

    #pragma unroll
    for (int i = 0; i < 8; ++i) {
        int idx = tid + i * 256;
        if (idx < 1920) {
            int rr = idx / 640;
            int rem = idx % 640;
            int w  = rem >> 3, cb = rem & 7;
            int wi = w + 1;
            int hr = h + rr - 1;
            half8 v = {};
            if (hr >= 0 && hr < HH)
                v = *(const half8*)(Xb + ((size_t)(hr * WW + w)) * CIN + cb * 8);
            int slot = cb ^ ((wi + (wi >> 3)) & 7);
            *(half8*)(&xs[(rr * 82 + wi) * 64 + slot * 8]) = v;
        }
    }
    if (tid < 48) {
        int cb = tid & 7;
        int wi = ((tid >> 3) & 1) ? 81 : 0;
        int rr = tid >> 4;
        int slot = cb ^ ((wi + (wi >> 3)) & 7);
        half8 z = {};
        *(half8*)(&xs[(rr * 82 + wi) * 64 + slot * 8]) = z;
    }
    __syncthreads();

    const int wid  = tid >> 6;
    const int lane = tid & 63;
    const int g = lane >> 4, r = lane & 15;
    const int o0 = (wid & 1) * 16;
    const int ti_lo = (wid >> 1) ? 3 : 0;
    const int ti_hi = (wid >> 1) ? 5 : 3;

    half8 aw[9][2];
    #pragma unroll
    for (int tap = 0; tap < 9; ++tap)
        #pragma unroll
        for (int ch = 0; ch < 2; ++ch)
            aw[tap][ch] = *(const half8*)(W9f + ((tap * 32 + o0 + r) * 64 + ch * 32 + g * 8));
    half8 gaf[2];
    if (src) {
        #pragma unroll
        for (int ch = 0; ch < 2; ++ch)
            gaf[ch] = *(const half8*)(GWf + ((o0 + r) * 64 + ch * 32 + g * 8));
    }

    f32x4 biasv, gbv = {0.f, 0.f, 0.f, 0.f};
    #pragma unroll
    for (int j = 0; j < 4; ++j) biasv[j] = shared_b[o0 + g * 4 + j];
    if (src) {
        #pragma unroll
        for (int j = 0; j < 4; ++j) gbv[j] = g_b[o0 + g * 4 + j];
    }

    for (int ti = ti_lo; ti < ti_hi; ++ti) {
        const int n0 = ti * 16;
        const int wi0 = n0 + r;
        f32x4 accE = biasv;
        f32x4 accO = {0.f, 0.f, 0.f, 0.f};
        f32x4 vacc = gbv;
        #pragma unroll
        for (int tap = 0; tap < 9; ++tap) {
            const int kh = tap / 3, kw = tap % 3;
            const int wi = wi0 + kw;
            const int swz = (wi + (wi >> 3)) & 7;
            #pragma unroll
            for (int ch = 0; ch < 2; ++ch) {
                half8 bf = *(const half8*)(&xs[(kh * 82 + wi) * 64 + (((ch * 4 + g) ^ swz) * 8)]);
                if (tap & 1) accO = __builtin_amdgcn_mfma_f32_16x16x32_f16(aw[tap][ch], bf, accO, 0, 0, 0);
                else         accE = __builtin_amdgcn_mfma_f32_16x16x32_f16(aw[tap][ch], bf, accE, 0, 0, 0);
                if (src && tap == 4)
                    vacc = __builtin_amdgcn_mfma_f32_16x16x32_f16(gaf[ch], bf, vacc, 0, 0, 0);
            }
        }
        const int n = h * WW + n0 + r;
        f32x4 acc;
        #pragma unroll
        for (int j = 0; j < 4; ++j) acc[j] = accE[j] + accO[j];
        half4 pk;
        #pragma unroll
        for (int j = 0; j < 4; ++j) pk[j] = (_Float16)acc[j];
        if (!src) {
            *(half4*)(Q + (size_t)(b * NSP + n) * ICH + o0 + g * 4) = pk;
        } else {
            *(half4*)(K + (size_t)(b * NSP + n) * ICH + o0 + g * 4) = pk;
            #pragma unroll
            for (int j = 0; j < 4; ++j)
                Vt[(size_t)(b * ICH + o0 + g * 4 + j) * NSP + n] = (_Float16)vacc[j];
        }
    }
}

// ---------------------------------------------------------------------------
// Kernel 2: flash attention (round-10/12 math, byte-identical numerics).
// ONE change: V LDS layout XOR-swizzled to kill the 4-way bank conflict on
// the b64 V fragment reads (bank was (4r+2g)%32 -> even banks only).
//   write: element 16*((va_c>>1)^(va_r&7)) + 8*(va_c&1)   [16B aligned]
//   read : element 16*(kh^(r&7)) + 4*g                     [8B aligned]
// Same involution on both sides => bit-identical data.
// ---------------------------------------------------------------------------
#define KPAD 40    /* K LDS row: 80 B  */
#define VPAD 136   /* V LDS row: 272 B (dword stride 68 == 4 mod 32) */

__global__ __launch_bounds__(256) void nlb_attn_kernel(
    const _Float16* __restrict__ Q, const _Float16* __restrict__ Km,
    const _Float16* __restrict__ Vt,
    float* __restrict__ YU, float* __restrict__ ML)
{
    const int bid = blockIdx.x;
    const int tg  = bid % QGROUPS;
    const int rem = bid / QGROUPS;
    const int b = rem & 1;
    const int s = rem >> 1;

    const int tid  = threadIdx.x;
    const int wid  = tid >> 6;
    const int lane = tid & 63;
    const int g = lane >> 4, r = lane & 15;

    __shared__ __align__(16) _Float16 Kls[2][KBLK][KPAD];
    __shared__ __align__(16) _Float16 Vls[2][ICH][VPAD];

    const _Float16* __restrict__ Qb = Q  + (size_t)b * NSP * ICH;
    const _Float16* __restrict__ Kb = Km + (size_t)b * NSP * ICH + (size_t)s * KRANGE * ICH;
    const _Float16* __restrict__ Vb = Vt + (size_t)b * ICH * NSP + s * KRANGE;

    const f32x4 zero4 = {0.f, 0.f, 0.f, 0.f};

    const int q0 = tg * 128 + wid * QBLK;
    half8 qa[2];
    #pragma unroll
    for (int qf = 0; qf < 2; ++qf)
        qa[qf] = *(const half8*)(Qb + (size_t)(q0 + qf * 16 + r) * ICH + g * 8);

    f32x4 yacc[2][2];
    float m2[2], lp[2];
    #pragma unroll
    for (int qf = 0; qf < 2; ++qf) {
        yacc[qf][0] = zero4; yacc[qf][1] = zero4;
        m2[qf] = -1e30f; lp[qf] = 0.f;
    }

    const int ka_r = tid >> 2,          ka_c = tid & 3;
    const int kb_r = (tid + 256) >> 2,  kb_c = (tid + 256) & 3;
    const int va_r = tid >> 4,          va_c = tid & 15;
    const int vb_r = (tid + 256) >> 4,  vb_c = (tid + 256) & 15;

    // swizzled V element offsets (per-thread constants)
    const int va_off = 16 * ((va_c >> 1) ^ (va_r & 7)) + 8 * (va_c & 1);
    const int vb_off = 16 * ((vb_c >> 1) ^ (vb_r & 7)) + 8 * (vb_c & 1);

    {
        *(half8*)(&Kls[0][ka_r][ka_c * 8]) = *(const half8*)(Kb + (size_t)ka_r * ICH + ka_c * 8);
        *(half8*)(&Kls[0][kb_r][kb_c * 8]) = *(const half8*)(Kb + (size_t)kb_r * ICH + kb_c * 8);
        *(half8*)(&Vls[0][va_r][va_off]) = *(const half8*)(Vb + (size_t)va_r * NSP + va_c * 8);
        *(half8*)(&Vls[0][vb_r][vb_off]) = *(const half8*)(Vb + (size_t)vb_r * NSP + vb_c * 8);
    }
    __syncthreads();

    int cur = 0;
    for (int it = 0; it < NITER; ++it) {
        const bool more = (it + 1 < NITER);
        half8 kst0, kst1, vst0, vst1;
        if (more) {
            const _Float16* Kn = Kb + (size_t)(it + 1) * KBLK * ICH;
            const _Float16* Vn = Vb + (size_t)(it + 1) * KBLK;
            kst0 = *(const half8*)(Kn + (size_t)ka_r * ICH + ka_c * 8);
            kst1 = *(const half8*)(Kn + (size_t)kb_r * ICH + kb_c * 8);
            vst0 = *(const half8*)(Vn + (size_t)va_r * NSP + va_c * 8);
            vst1 = *(const half8*)(Vn + (size_t)vb_r * NSP + vb_c * 8);
        }

        half8 kf[8];
        #pragma unroll
        for (int kh = 0; kh < 8; ++kh)
            kf[kh] = *(const half8*)(&Kls[cur][kh * 16 + r][g * 8]);

        #pragma unroll
        for (int qf = 0; qf < 2; ++qf) {
            f32x4 sa[8];
            __builtin_amdgcn_s_setprio(1);
            #pragma unroll
            for (int kh = 0; kh < 8; ++kh)
                sa[kh] = __builtin_amdgcn_mfma_f32_16x16x32_f16(kf[kh], qa[qf], zero4, 0, 0, 0);
            __builtin_amdgcn_s_setprio(0);

            float vmax = -1e30f;
            #pragma unroll
            for (int kh = 0; kh < 8; ++kh)
                vmax = fmaxf(vmax, fmaxf(fmaxf(sa[kh][0], sa[kh][1]),
                                         fmaxf(sa[kh][2], sa[kh][3])));
            if (__any(vmax - m2[qf] > 8.f)) {
                float tm = vmax;
                tm = fmaxf(tm, __shfl_xor(tm, 16));
                tm = fmaxf(tm, __shfl_xor(tm, 32));
                float mn = fmaxf(m2[qf], tm);
                float sc = __expf(m2[qf] - mn);
                m2[qf] = mn; lp[qf] *= sc;
                #pragma unroll
                for (int j = 0; j < 4; ++j) { yacc[qf][0][j] *= sc; yacc[qf][1][j] *= sc; }
            }

            #pragma unroll
            for (int kh = 0; kh < 8; ++kh) {
                half4 pk; float ls = 0.f;
                #pragma unroll
                for (int j = 0; j < 4; ++j) {
                    float p = __expf(sa[kh][j] - m2[qf]);
                    ls += p; pk[j] = (_Float16)p;
                }
                lp[qf] += ls;
                const int voff = 16 * (kh ^ (r & 7)) + 4 * g;   // swizzled read
                half4 vfa = *(const half4*)(&Vls[cur][r][voff]);
                half4 vfb = *(const half4*)(&Vls[cur][16 + r][voff]);
                yacc[qf][0] = __builtin_amdgcn_mfma_f32_16x16x16f16(vfa, pk, yacc[qf][0], 0, 0, 0);
                yacc[qf][1] = __builtin_amdgcn_mfma_f32_16x16x16f16(vfb, pk, yacc[qf][1], 0, 0, 0);
            }
        }

        if (more) {
            *(half8*)(&Kls[cur ^ 1][ka_r][ka_c * 8]) = kst0;
            *(half8*)(&Kls[cur ^ 1][kb_r][kb_c * 8]) = kst1;
            *(half8*)(&Vls[cur ^ 1][va_r][va_off]) = vst0;
            *(half8*)(&Vls[cur ^ 1][vb_r][vb_off]) = vst1;
        }
        __syncthreads();
        cur ^= 1;
    }

    #pragma unroll
    for (int qf = 0; qf < 2; ++qf) {
        float lv = lp[qf];
        lv += __shfl_xor(lv, 16);
        lv += __shfl_xor(lv, 32);
        if (g == 0) {
            size_t base = ((size_t)(s * NB + b) * NSP + q0 + qf * 16 + r) * 2;
            ML[base + 0] = m2[qf];
            ML[base + 1] = lv;
        }
        #pragma unroll
        for (int ch = 0; ch < 2; ++ch)
            *(f32x4*)(YU + ((size_t)(s * NB + b) * NSP + q0 + qf * 16 + r) * ICH
                      + ch * 16 + g * 4) = yacc[qf][ch];
    }
}

// ---------------------------------------------------------------------------
// Kernel 3: combine k-splits, normalize, fused W 1x1 projection + bias +
// residual (round-12, 400 blocks x 32 rows).
// ---------------------------------------------------------------------------
__global__ __launch_bounds__(256) void nlb_combine_kernel(
    const float* __restrict__ YU, const float* __restrict__ ML,
    const float* __restrict__ W_w, const float* __restrict__ W_b,
    const float* __restrict__ x, float* __restrict__ out)
{
    const int bid = blockIdx.x;
    const int b = bid / 200;
    const int rowbase = (bid % 200) * 32;

    __shared__ float ylds[32][33];
    __shared__ float wwl[CIN * ICH];

    const int tid = threadIdx.x;
    for (int e = tid; e < CIN * ICH; e += 256) wwl[e] = W_w[e];

    #pragma unroll
    for (int i = 0; i < 4; ++i) {
        int idx = tid + i * 256;
        int row = idx >> 5, c = idx & 31;
        int grow = rowbase + row;
        float m[KSPLIT], lv[KSPLIT], M = -1e30f;
        #pragma unroll
        for (int s2 = 0; s2 < KSPLIT; ++s2) {
            size_t base = ((size_t)(s2 * NB + b) * NSP + grow) * 2;
            m[s2]  = ML[base + 0];
            lv[s2] = ML[base + 1];
            M = fmaxf(M, m[s2]);
        }
        float denom = 0.f, acc = 0.f;
        #pragma unroll
        for (int s2 = 0; s2 < KSPLIT; ++s2) {
            float e2 = __expf(m[s2] - M);
            denom += lv[s2] * e2;
            acc += YU[((size_t)(s2 * NB + b) * NSP + grow) * ICH + c] * e2;
        }
        ylds[row][c] = acc / denom;
    }
    __syncthreads();

    const int row = tid & 31;
    const int o0  = tid >> 5;
    #pragma unroll
    for (int k = 0; k < 8; ++k) {
        int o = o0 * 8 + k;
        size_t gi = (size_t)(b * CIN + o) * NSP + rowbase + row;
        float accv = W_b[o] + x[gi];
        #pragma unroll
        for (int c = 0; c < ICH; ++c) accv += wwl[o * ICH + c] * ylds[row][c];
        out[gi] = accv;
    }
}

// ---------------------------------------------------------------------------
extern "C" void kernel_launch(void* const* d_in, const int* in_sizes, int n_in,
                              void* d_out, int out_size, void* d_ws, size_t ws_size,
                              hipStream_t stream) {
    const float* x        = (const float*)d_in[0];
    const float* x_t      = (const float*)d_in[1];
    const float* g_w      = (const float*)d_in[2];
    const float* g_b      = (const float*)d_in[3];
    const float* W_w      = (const float*)d_in[4];
    const float* W_b      = (const float*)d_in[5];
    const float* shared_w = (const float*)d_in[6];
    const float* shared_b = (const float*)d_in[7];
    float* out = (float*)d_out;

    char* ws = (char*)d_ws;
    _Float16* Q    = (_Float16*)(ws);                  //   819,200 B
    _Float16* K    = (_Float16*)(ws + 819200);         //   819,200 B
    _Float16* Vt   = (_Float16*)(ws + 1638400);        //   819,200 B
    float*    YU   = (float*)(ws + 2457600);           // 8,192,000 B
    float*    ML   = (float*)(ws + 10649600);          //   512,000 B
    _Float16* W9f  = (_Float16*)(ws + 11161600);       //    36,864 B
    _Float16* GWf  = (_Float16*)(ws + 11198464);       //     4,096 B
    _Float16* Xf16 = (_Float16*)(ws + 11202560);       // 3,276,800 B (total ~14.5 MB)

    hipLaunchKernelGGL(nlb_trans_kernel, dim3(400), dim3(256), 0, stream,
                       x, x_t, shared_w, g_w, Xf16, W9f, GWf);
    hipLaunchKernelGGL(nlb_conv_mfma_kernel, dim3(320), dim3(256), 0, stream,
                       Xf16, W9f, GWf, shared_b, g_b, Q, K, Vt);
    hipLaunchKernelGGL(nlb_attn_kernel, dim3(NB * QGROUPS * KSPLIT), dim3(256), 0, stream,
                       Q, K, Vt, YU, ML);
    hipLaunchKernelGGL(nlb_combine_kernel, dim3(400), dim3(256), 0, stream,
                       YU, ML, W_w, W_b, x, out);
}

// Round 16
// 57.072 us; speedup vs baseline: 2.8423x; 1.0554x over previous
//
#include <hip/hip_runtime.h>

typedef __attribute__((ext_vector_type(8))) _Float16 half8;
typedef __attribute__((ext_vector_type(4))) _Float16 half4;
typedef __attribute__((ext_vector_type(4))) float f32x4;

#define NB 2
#define CIN 64
#define ICH 32
#define HH 80
#define WW 80
#define NSP 6400
#define KSPLIT 5
#define KRANGE 1280
#define KBLK 128
#define NITER 10
#define QBLK 32
#define QGROUPS 50   /* 128 q-rows per block */

#if __has_builtin(__builtin_amdgcn_exp2f)
#define EXP2F(x) __builtin_amdgcn_exp2f(x)
#else
#define EXP2F(x) exp2f(x)
#endif

// ---------------------------------------------------------------------------
// Kernel 0: input transpose (f32 NCHW -> f16 [src][b][n][c]) + weight prep.
// ---------------------------------------------------------------------------
__global__ __launch_bounds__(256) void nlb_trans_kernel(
    const float* __restrict__ x, const float* __restrict__ x_t,
    const float* __restrict__ shared_w, const float* __restrict__ g_w,
    _Float16* __restrict__ Xf16, _Float16* __restrict__ W9f,
    _Float16* __restrict__ GWf)
{
    const int bid = blockIdx.x;
    const int tid = threadIdx.x;

    if (bid >= 320) {
        int e = (bid - 320) * 256 + tid;
        if (e < 9 * 32 * 64) {
            int c = e & 63, o = (e >> 6) & 31, tap = e >> 11;
            W9f[e] = (_Float16)shared_w[(o * 64 + c) * 9 + tap];
        } else {
            int e2 = e - 9 * 32 * 64;
            GWf[e2] = (_Float16)g_w[e2];
        }
        return;
    }

    const int src = bid & 1;
    const int b   = (bid >> 1) & 1;
    const int h   = bid >> 2;
    const float* __restrict__ in = src ? x_t : x;

    __shared__ float ts[CIN][WW + 1];

    #pragma unroll
    for (int i = 0; i < 5; ++i) {
        int idx = tid + i * 256;
        int c = idx / 20, w4 = idx % 20;
        float4 v = *(const float4*)(in + ((size_t)(b * CIN + c) * HH + h) * WW + w4 * 4);
        ts[c][w4 * 4 + 0] = v.x;
        ts[c][w4 * 4 + 1] = v.y;
        ts[c][w4 * 4 + 2] = v.z;
        ts[c][w4 * 4 + 3] = v.w;
    }
    __syncthreads();

    _Float16* __restrict__ dst = Xf16 + ((size_t)(src * NB + b) * NSP + h * WW) * CIN;
    #pragma unroll
    for (int i = 0; i < 3; ++i) {
        int idx = tid + i * 256;
        if (idx < 640) {
            int w = idx >> 3, cb = idx & 7;
            half8 o;
            #pragma unroll
            for (int k = 0; k < 8; ++k) o[k] = (_Float16)ts[cb * 8 + k][w];
            *(half8*)(dst + (size_t)w * CIN + cb * 8) = o;
        }
    }
}

// ---------------------------------------------------------------------------
// Kernel 1: implicit-GEMM 3x3 conv via MFMA + fused 1x1 g-conv (round-12).
// ONE numerics change: Q is pre-scaled by log2(e) in the f32 epilogue so
// attention runs in the exp2 domain.
// ---------------------------------------------------------------------------
__global__ __launch_bounds__(256) void nlb_conv_mfma_kernel(
    const _Float16* __restrict__ Xf16,
    const _Float16* __restrict__ W9f, const _Float16* __restrict__ GWf,
    const float* __restrict__ shared_b, const float* __restrict__ g_b,
    _Float16* __restrict__ Q, _Float16* __restrict__ K, _Float16* __restrict__ Vt)
{
    const int bid = blockIdx.x;
    const int src = bid & 1;
    const int b   = (bid >> 1) & 1;
    const int h   = bid >> 2;

    __shared__ _Float16 xs[3 * 82 * 64];

    const int tid = threadIdx.x;
    const _Float16* __restrict__ Xb = Xf16 + (size_t)(src * NB + b) * NSP * CIN;

    #pragma unroll
    for (int i = 0; i < 8; ++i) {
        int idx = tid + i * 256;
        if (idx < 1920) {
            int rr = idx / 640;
            int rem = idx % 640;
            int w  = rem >> 3, cb = rem & 7;
            int wi = w + 1;
            int hr = h + rr - 1;
            half8 v = {};
            if (hr >= 0 && hr < HH)
                v = *(const half8*)(Xb + ((size_t)(hr * WW + w)) * CIN + cb * 8);
            int slot = cb ^ ((wi + (wi >> 3)) & 7);
            *(half8*)(&xs[(rr * 82 + wi) * 64 + slot * 8]) = v;
        }
    }
    if (tid < 48) {
        int cb = tid & 7;
        int wi = ((tid >> 3) & 1) ? 81 : 0;
        int rr = tid >> 4;
        int slot = cb ^ ((wi + (wi >> 3)) & 7);
        half8 z = {};
        *(half8*)(&xs[(rr * 82 + wi) * 64 + slot * 8]) = z;
    }
    __syncthreads();

    const int wid  = tid >> 6;
    const int lane = tid & 63;
    const int g = lane >> 4, r = lane & 15;
    const int o0 = (wid & 1) * 16;
    const int ti_lo = (wid >> 1) ? 3 : 0;
    const int ti_hi = (wid >> 1) ? 5 : 3;

    half8 aw[9][2];
    #pragma unroll
    for (int tap = 0; tap < 9; ++tap)
        #pragma unroll
        for (int ch = 0; ch < 2; ++ch)
            aw[tap][ch] = *(const half8*)(W9f + ((tap * 32 + o0 + r) * 64 + ch * 32 + g * 8));
    half8 gaf[2];
    if (src) {
        #pragma unroll
        for (int ch = 0; ch < 2; ++ch)
            gaf[ch] = *(const half8*)(GWf + ((o0 + r) * 64 + ch * 32 + g * 8));
    }

    f32x4 biasv, gbv = {0.f, 0.f, 0.f, 0.f};
    #pragma unroll
    for (int j = 0; j < 4; ++j) biasv[j] = shared_b[o0 + g * 4 + j];
    if (src) {
        #pragma unroll
        for (int j = 0; j < 4; ++j) gbv[j] = g_b[o0 + g * 4 + j];
    }

    const float LOG2E = 1.4426950408889634f;

    for (int ti = ti_lo; ti < ti_hi; ++ti) {
        const int n0 = ti * 16;
        const int wi0 = n0 + r;
        f32x4 accE = biasv;
        f32x4 accO = {0.f, 0.f, 0.f, 0.f};
        f32x4 vacc = gbv;
        #pragma unroll
        for (int tap = 0; tap < 9; ++tap) {
            const int kh = tap / 3, kw = tap % 3;
            const int wi = wi0 + kw;
            const int swz = (wi + (wi >> 3)) & 7;
            #pragma unroll
            for (int ch = 0; ch < 2; ++ch) {
                half8 bf = *(const half8*)(&xs[(kh * 82 + wi) * 64 + (((ch * 4 + g) ^ swz) * 8)]);
                if (tap & 1) accO = __builtin_amdgcn_mfma_f32_16x16x32_f16(aw[tap][ch], bf, accO, 0, 0, 0);
                else         accE = __builtin_amdgcn_mfma_f32_16x16x32_f16(aw[tap][ch], bf, accE, 0, 0, 0);
                if (src && tap == 4)
                    vacc = __builtin_amdgcn_mfma_f32_16x16x32_f16(gaf[ch], bf, vacc, 0, 0, 0);
            }
        }
        const int n = h * WW + n0 + r;
        f32x4 acc;
        #pragma unroll
        for (int j = 0; j < 4; ++j) acc[j] = accE[j] + accO[j];
        half4 pk;
        if (!src) {
            #pragma unroll
            for (int j = 0; j < 4; ++j) pk[j] = (_Float16)(acc[j] * LOG2E);
            *(half4*)(Q + (size_t)(b * NSP + n) * ICH + o0 + g * 4) = pk;
        } else {
            #pragma unroll
            for (int j = 0; j < 4; ++j) pk[j] = (_Float16)acc[j];
            *(half4*)(K + (size_t)(b * NSP + n) * ICH + o0 + g * 4) = pk;
            #pragma unroll
            for (int j = 0; j < 4; ++j)
                Vt[(size_t)(b * ICH + o0 + g * 4 + j) * NSP + n] = (_Float16)vacc[j];
        }
    }
}

// ---------------------------------------------------------------------------
// Kernel 2: flash attention, exp2 domain. Restructured iteration:
//   S-MFMAs (both qf, clustered) -> softmax (both qf, exps clustered) ->
//   single PV loop with V fragments read ONCE and shared across qf
//   (they were read twice before - pure redundancy).
// Numerics otherwise identical; V LDS swizzle kept.
// ---------------------------------------------------------------------------
#define KPAD 40    /* K LDS row: 80 B  */
#define VPAD 136   /* V LDS row: 272 B */

__global__ __launch_bounds__(256) void nlb_attn_kernel(
    const _Float16* __restrict__ Q, const _Float16* __restrict__ Km,
    const _Float16* __restrict__ Vt,
    float* __restrict__ YU, float* __restrict__ ML)
{
    const int bid = blockIdx.x;
    const int tg  = bid % QGROUPS;
    const int rem = bid / QGROUPS;
    const int b = rem & 1;
    const int s = rem >> 1;

    const int tid  = threadIdx.x;
    const int wid  = tid >> 6;
    const int lane = tid & 63;
    const int g = lane >> 4, r = lane & 15;

    __shared__ __align__(16) _Float16 Kls[2][KBLK][KPAD];
    __shared__ __align__(16) _Float16 Vls[2][ICH][VPAD];

    const _Float16* __restrict__ Qb = Q  + (size_t)b * NSP * ICH;
    const _Float16* __restrict__ Kb = Km + (size_t)b * NSP * ICH + (size_t)s * KRANGE * ICH;
    const _Float16* __restrict__ Vb = Vt + (size_t)b * ICH * NSP + s * KRANGE;

    const f32x4 zero4 = {0.f, 0.f, 0.f, 0.f};

    const int q0 = tg * 128 + wid * QBLK;
    half8 qa[2];
    #pragma unroll
    for (int qf = 0; qf < 2; ++qf)
        qa[qf] = *(const half8*)(Qb + (size_t)(q0 + qf * 16 + r) * ICH + g * 8);

    f32x4 yacc[2][2];
    float m2[2], lp[2];
    #pragma unroll
    for (int qf = 0; qf < 2; ++qf) {
        yacc[qf][0] = zero4; yacc[qf][1] = zero4;
        m2[qf] = -1e30f; lp[qf] = 0.f;
    }

    const int ka_r = tid >> 2,          ka_c = tid & 3;
    const int kb_r = (tid + 256) >> 2,  kb_c = (tid + 256) & 3;
    const int va_r = tid >> 4,          va_c = tid & 15;
    const int vb_r = (tid + 256) >> 4,  vb_c = (tid + 256) & 15;

    const int va_off = 16 * ((va_c >> 1) ^ (va_r & 7)) + 8 * (va_c & 1);
    const int vb_off = 16 * ((vb_c >> 1) ^ (vb_r & 7)) + 8 * (vb_c & 1);

    {
        *(half8*)(&Kls[0][ka_r][ka_c * 8]) = *(const half8*)(Kb + (size_t)ka_r * ICH + ka_c * 8);
        *(half8*)(&Kls[0][kb_r][kb_c * 8]) = *(const half8*)(Kb + (size_t)kb_r * ICH + kb_c * 8);
        *(half8*)(&Vls[0][va_r][va_off]) = *(const half8*)(Vb + (size_t)va_r * NSP + va_c * 8);
        *(half8*)(&Vls[0][vb_r][vb_off]) = *(const half8*)(Vb + (size_t)vb_r * NSP + vb_c * 8);
    }
    __syncthreads();

    int cur = 0;
    for (int it = 0; it < NITER; ++it) {
        const bool more = (it + 1 < NITER);
        half8 kst0, kst1, vst0, vst1;
        if (more) {
            const _Float16* Kn = Kb + (size_t)(it + 1) * KBLK * ICH;
            const _Float16* Vn = Vb + (size_t)(it + 1) * KBLK;
            kst0 = *(const half8*)(Kn + (size_t)ka_r * ICH + ka_c * 8);
            kst1 = *(const half8*)(Kn + (size_t)kb_r * ICH + kb_c * 8);
            vst0 = *(const half8*)(Vn + (size_t)va_r * NSP + va_c * 8);
            vst1 = *(const half8*)(Vn + (size_t)vb_r * NSP + vb_c * 8);
        }

        half8 kf[8];
        #pragma unroll
        for (int kh = 0; kh < 8; ++kh)
            kf[kh] = *(const half8*)(&Kls[cur][kh * 16 + r][g * 8]);

        // ---- S = K Q^T for both q-fragments (clustered MFMAs) ----
        f32x4 sa[2][8];
        __builtin_amdgcn_s_setprio(1);
        #pragma unroll
        for (int qf = 0; qf < 2; ++qf)
            #pragma unroll
            for (int kh = 0; kh < 8; ++kh)
                sa[qf][kh] = __builtin_amdgcn_mfma_f32_16x16x32_f16(kf[kh], qa[qf], zero4, 0, 0, 0);
        __builtin_amdgcn_s_setprio(0);

        // ---- softmax (exp2 domain) for both qf; exps clustered ----
        half4 pk[2][8];
        #pragma unroll
        for (int qf = 0; qf < 2; ++qf) {
            float vmax = -1e30f;
            #pragma unroll
            for (int kh = 0; kh < 8; ++kh)
                vmax = fmaxf(vmax, fmaxf(fmaxf(sa[qf][kh][0], sa[qf][kh][1]),
                                         fmaxf(sa[qf][kh][2], sa[qf][kh][3])));
            if (__any(vmax - m2[qf] > 11.f)) {
                float tm = vmax;
                tm = fmaxf(tm, __shfl_xor(tm, 16));
                tm = fmaxf(tm, __shfl_xor(tm, 32));
                float mn = fmaxf(m2[qf], tm);
                float sc = EXP2F(m2[qf] - mn);
                m2[qf] = mn; lp[qf] *= sc;
                #pragma unroll
                for (int j = 0; j < 4; ++j) { yacc[qf][0][j] *= sc; yacc[qf][1][j] *= sc; }
            }
            #pragma unroll
            for (int kh = 0; kh < 8; ++kh) {
                float ls = 0.f;
                #pragma unroll
                for (int j = 0; j < 4; ++j) {
                    float p = EXP2F(sa[qf][kh][j] - m2[qf]);
                    ls += p; pk[qf][kh][j] = (_Float16)p;
                }
                lp[qf] += ls;
            }
        }

        // ---- PV: V fragments read ONCE, shared across both qf ----
        #pragma unroll
        for (int kh = 0; kh < 8; ++kh) {
            const int voff = 16 * (kh ^ (r & 7)) + 4 * g;
            half4 vfa = *(const half4*)(&Vls[cur][r][voff]);
            half4 vfb = *(const half4*)(&Vls[cur][16 + r][voff]);
            #pragma unroll
            for (int qf = 0; qf < 2; ++qf) {
                yacc[qf][0] = __builtin_amdgcn_mfma_f32_16x16x16f16(vfa, pk[qf][kh], yacc[qf][0], 0, 0, 0);
                yacc[qf][1] = __builtin_amdgcn_mfma_f32_16x16x16f16(vfb, pk[qf][kh], yacc[qf][1], 0, 0, 0);
            }
        }

        if (more) {
            *(half8*)(&Kls[cur ^ 1][ka_r][ka_c * 8]) = kst0;
            *(half8*)(&Kls[cur ^ 1][kb_r][kb_c * 8]) = kst1;
            *(half8*)(&Vls[cur ^ 1][va_r][va_off]) = vst0;
            *(half8*)(&Vls[cur ^ 1][vb_r][vb_off]) = vst1;
        }
        __syncthreads();
        cur ^= 1;
    }

    #pragma unroll
    for (int qf = 0; qf < 2; ++qf) {
        float lv = lp[qf];
        lv += __shfl_xor(lv, 16);
        lv += __shfl_xor(lv, 32);
        if (g == 0) {
            size_t base = ((size_t)(s * NB + b) * NSP + q0 + qf * 16 + r) * 2;
            ML[base + 0] = m2[qf];     // log2-domain running max
            ML[base + 1] = lv;
        }
        #pragma unroll
        for (int ch = 0; ch < 2; ++ch)
            *(f32x4*)(YU + ((size_t)(s * NB + b) * NSP + q0 + qf * 16 + r) * ICH
                      + ch * 16 + g * 4) = yacc[qf][ch];
    }
}

// ---------------------------------------------------------------------------
// Kernel 3: combine k-splits (exp2-domain weights), normalize, fused W 1x1
// projection + bias + residual (round-12, 400 blocks x 32 rows).
// ---------------------------------------------------------------------------
__global__ __launch_bounds__(256) void nlb_combine_kernel(
    const float* __restrict__ YU, const float* __restrict__ ML,
    const float* __restrict__ W_w, const float* __restrict__ W_b,
    const float* __restrict__ x, float* __restrict__ out)
{
    const int bid = blockIdx.x;
    const int b = bid / 200;
    const int rowbase = (bid % 200) * 32;

    __shared__ float ylds[32][33];
    __shared__ float wwl[CIN * ICH];

    const int tid = threadIdx.x;
    for (int e = tid; e < CIN * ICH; e += 256) wwl[e] = W_w[e];

    #pragma unroll
    for (int i = 0; i < 4; ++i) {
        int idx = tid + i * 256;
        int row = idx >> 5, c = idx & 31;
        int grow = rowbase + row;
        float m[KSPLIT], lv[KSPLIT], M = -1e30f;
        #pragma unroll
        for (int s2 = 0; s2 < KSPLIT; ++s2) {
            size_t base = ((size_t)(s2 * NB + b) * NSP + grow) * 2;
            m[s2]  = ML[base + 0];
            lv[s2] = ML[base + 1];
            M = fmaxf(M, m[s2]);
        }
        float denom = 0.f, acc = 0.f;
        #pragma unroll
        for (int s2 = 0; s2 < KSPLIT; ++s2) {
            float e2 = exp2f(m[s2] - M);
            denom += lv[s2] * e2;
            acc += YU[((size_t)(s2 * NB + b) * NSP + grow) * ICH + c] * e2;
        }
        ylds[row][c] = acc / denom;
    }
    __syncthreads();

    const int row = tid & 31;
    const int o0  = tid >> 5;
    #pragma unroll
    for (int k = 0; k < 8; ++k) {
        int o = o0 * 8 + k;
        size_t gi = (size_t)(b * CIN + o) * NSP + rowbase + row;
        float accv = W_b[o] + x[gi];
        #pragma unroll
        for (int c = 0; c < ICH; ++c) accv += wwl[o * ICH + c] * ylds[row][c];
        out[gi] = accv;
    }
}

// ---------------------------------------------------------------------------
extern "C" void kernel_launch(void* const* d_in, const int* in_sizes, int n_in,
                              void* d_out, int out_size, void* d_ws, size_t ws_size,
                              hipStream_t stream) {
    const float* x        = (const float*)d_in[0];
    const float* x_t      = (const float*)d_in[1];
    const float* g_w      = (const float*)d_in[2];
    const float* g_b      = (const float*)d_in[3];
    const float* W_w      = (const float*)d_in[4];
    const float* W_b      = (const float*)d_in[5];
    const float* shared_w = (const float*)d_in[6];
    const float* shared_b = (const float*)d_in[7];
    float* out = (float*)d_out;

    char* ws = (char*)d_ws;
    _Float16* Q    = (_Float16*)(ws);                  //   819,200 B
    _Float16* K    = (_Float16*)(ws + 819200);         //   819,200 B
    _Float16* Vt   = (_Float16*)(ws + 1638400);        //   819,200 B
    float*    YU   = (float*)(ws + 2457600);           // 8,192,000 B
    float*    ML   = (float*)(ws + 10649600);          //   512,000 B
    _Float16* W9f  = (_Float16*)(ws + 11161600);       //    36,864 B
    _Float16* GWf  = (_Float16*)(ws + 11198464);       //     4,096 B
    _Float16* Xf16 = (_Float16*)(ws + 11202560);       // 3,276,800 B (total ~14.5 MB)

    hipLaunchKernelGGL(nlb_trans_kernel, dim3(400), dim3(256), 0, stream,
                       x, x_t, shared_w, g_w, Xf16, W9f, GWf);
    hipLaunchKernelGGL(nlb_conv_mfma_kernel, dim3(320), dim3(256), 0, stream,
                       Xf16, W9f, GWf, shared_b, g_b, Q, K, Vt);
    hipLaunchKernelGGL(nlb_attn_kernel, dim3(NB * QGROUPS * KSPLIT), dim3(256), 0, stream,
                       Q, K, Vt, YU, ML);
    hipLaunchKernelGGL(nlb_combine_kernel, dim3(400), dim3(256), 0, stream,
                       YU, ML, W_w, W_b, x, out);
}